// Round 3
// baseline (92.786 us; speedup 1.0000x reference)
//
#include <hip/hip_runtime.h>

#define N 8192
#define TILE 64
#define T (N / TILE)     // 128 tiles
#define SOFT2 1.0e-4f    // 0.01^2

// Newton-3rd-law tiled kernel. One 64-lane wave per block handles one
// unordered tile pair (TI, TJ), covered exactly once via wrapped diagonals:
//   blockIdx.x = TI in [0,128), blockIdx.y = q in [0,64]
//   TJ = (TI + q) % T;  q=0 -> diagonal (no symmetry);
//   q=64 -> antipodal pair, only TI<64 proceed (TI and TI+64 give same pair).
// Off-diagonal: lane l owns i = TI*64+l (register accum) and steps the
// skewed j = (l+k)&63 so each step touches 64 distinct j's -> the LDS
// reaction-accumulator RMW is race-free within the lock-step wave.
// Each retained pair shares one rsq for both force directions.
__global__ __launch_bounds__(TILE) void nbody_sym(
    const float* __restrict__ pos, const float* __restrict__ mass,
    float* __restrict__ out) {
  const int TI = blockIdx.x;
  const int q = blockIdx.y;
  const int TJ = (TI + q) & (T - 1);
  if (q == T / 2 && TI >= T / 2) return;  // antipodal pairs: half the blocks

  __shared__ float4 jb[TILE];    // j-tile bodies: x,y,z,mass
  __shared__ float4 jacc[TILE];  // reaction accumulators (w unused)

  const int l = threadIdx.x;
  const int i = TI * TILE + l;
  const int j = TJ * TILE + l;

  jb[l] = make_float4(pos[j * 3 + 0], pos[j * 3 + 1], pos[j * 3 + 2], mass[j]);
  jacc[l] = make_float4(0.f, 0.f, 0.f, 0.f);

  const float xi = pos[i * 3 + 0];
  const float yi = pos[i * 3 + 1];
  const float zi = pos[i * 3 + 2];
  const float mi = mass[i];

  float ax = 0.f, ay = 0.f, az = 0.f;
  __syncthreads();  // single wave: compiles to waitcnt (+barrier), cheap

  if (q == 0) {
    // Diagonal tile: plain one-directional loop; j==i contributes exactly 0
    // (diff = 0, r2 = SOFT2 -> w*0 = 0), matching the reference.
#pragma unroll 8
    for (int k = 0; k < TILE; ++k) {
      float4 o = jb[k];  // wave-uniform -> LDS broadcast
      float dx = o.x - xi;
      float dy = o.y - yi;
      float dz = o.z - zi;
      float r2 = fmaf(dx, dx, fmaf(dy, dy, fmaf(dz, dz, SOFT2)));
      float inv = __builtin_amdgcn_rsqf(r2);
      float w = o.w * (inv * inv * inv);
      ax = fmaf(w, dx, ax);
      ay = fmaf(w, dy, ay);
      az = fmaf(w, dz, az);
    }
    atomicAdd(&out[i * 3 + 0], ax);
    atomicAdd(&out[i * 3 + 1], ay);
    atomicAdd(&out[i * 3 + 2], az);
  } else {
    // Off-diagonal: both force directions per pair, one rsq.
#pragma unroll 8
    for (int k = 0; k < TILE; ++k) {
      const int jj = (l + k) & (TILE - 1);
      float4 o = jb[jj];
      float dx = o.x - xi;  // d = r_j - r_i
      float dy = o.y - yi;
      float dz = o.z - zi;
      float r2 = fmaf(dx, dx, fmaf(dy, dy, fmaf(dz, dz, SOFT2)));
      float inv = __builtin_amdgcn_rsqf(r2);
      float inv3 = inv * inv * inv;
      float wj = o.w * inv3;  // m_j * r^-3 -> acts on i
      float wi = mi * inv3;   // m_i * r^-3 -> reaction on j
      ax = fmaf(wj, dx, ax);
      ay = fmaf(wj, dy, ay);
      az = fmaf(wj, dz, az);
      float4 acc = jacc[jj];  // race-free: distinct jj per lane this step
      acc.x = fmaf(-wi, dx, acc.x);
      acc.y = fmaf(-wi, dy, acc.y);
      acc.z = fmaf(-wi, dz, acc.z);
      jacc[jj] = acc;
    }
    atomicAdd(&out[i * 3 + 0], ax);
    atomicAdd(&out[i * 3 + 1], ay);
    atomicAdd(&out[i * 3 + 2], az);
    __syncthreads();  // make all lanes' jacc writes visible
    float4 ja = jacc[l];
    atomicAdd(&out[j * 3 + 0], ja.x);
    atomicAdd(&out[j * 3 + 1], ja.y);
    atomicAdd(&out[j * 3 + 2], ja.z);
  }
}

extern "C" void kernel_launch(void* const* d_in, const int* in_sizes, int n_in,
                              void* d_out, int out_size, void* d_ws,
                              size_t ws_size, hipStream_t stream) {
  const float* pos = (const float*)d_in[0];
  const float* mass = (const float*)d_in[1];
  float* out = (float*)d_out;

  // Atomic accumulation needs zeros (d_out is poisoned to 0xAA pre-launch).
  hipMemsetAsync(d_out, 0, (size_t)out_size * sizeof(float), stream);

  nbody_sym<<<dim3(T, T / 2 + 1), TILE, 0, stream>>>(pos, mass, out);
}